// Round 6
// baseline (12835.027 us; speedup 1.0000x reference)
//
#include <hip/hip_runtime.h>
#include <math.h>

#define NBLK 256
#define TPB  256

// ws float offsets
#define OFF_TOKPROJ 0        // 64*192 = 12288
#define OFF_A       12288    // 64*64
#define OFF_AVEC    16384    // 64
#define OFF_G       16448    // 64*192
#define OFF_CVEC    28736    // 192
#define OFF_HEADT   28928    // 64*64
#define OFF_SLOTS   33024    // 256*256 u64 = 131072 floats
#define OFF_MBF     164096   // 1024*256*64 ushort = 8388608 floats
#define WS_NEED_BF16 ((size_t)(OFF_MBF + 8388608) * 4)

#define MASK44 ((1ULL << 44) - 1)
#define MARK   (1ULL << 44)
#define THRESH (512ULL << 30)   // mean > 0.5  <=>  sum(prob*2^30) > 512*2^30

__device__ __forceinline__ float sigf(float x) { return 1.f / (1.f + expf(-x)); }

__device__ __forceinline__ unsigned short f2bf(float f) {
    unsigned int u = __float_as_uint(f);
    unsigned int r = (u + 0x7fffu + ((u >> 16) & 1u)) >> 16;   // RNE
    return (unsigned short)r;
}

// ---------------- prep: fused tables, zero slots, bf16 memory copy ----------
__global__ __launch_bounds__(64) void prep_k(
    const float* __restrict__ embed, const float* __restrict__ gwih,
    const float* __restrict__ gbih, const float* __restrict__ qw,
    const float* __restrict__ qb, const float* __restrict__ kw,
    const float* __restrict__ vw, const float* __restrict__ vb,
    const float* __restrict__ hw, const float* __restrict__ memory,
    float* __restrict__ ws)
{
    int blk = blockIdx.x, l = threadIdx.x;
    float* tokproj = ws + OFF_TOKPROJ;
    float* A = ws + OFF_A;
    float* avec = ws + OFF_AVEC;
    float* G = ws + OFF_G;
    float* cvec = ws + OFF_CVEC;
    float* headT = ws + OFF_HEADT;

    if (blk < 64) {
        int v = blk;
        for (int j = l; j < 192; j += 64) {
            float s = gbih[j];
            for (int d = 0; d < 64; ++d) s += embed[v * 64 + d] * gwih[j * 128 + d];
            tokproj[v * 192 + j] = s;
        }
    } else if (blk < 128) {
        int d = blk - 64;
        float s = 0.f;
        for (int e = 0; e < 64; ++e) s += qw[e * 64 + d] * kw[e * 64 + l];
        A[d * 64 + l] = s * 0.125f;   // 1/sqrt(64)
    } else if (blk < 192) {
        int e = blk - 128;
        for (int jj = 0; jj < 3; ++jj) {
            int j = jj * 64 + l;
            float s = 0.f;
            for (int d = 0; d < 64; ++d) s += vw[d * 64 + e] * gwih[j * 128 + 64 + d];
            G[e * 192 + j] = s;
        }
    } else if (blk == 192) {
        float s = 0.f;
        for (int e = 0; e < 64; ++e) s += qb[e] * kw[e * 64 + l];
        avec[l] = s * 0.125f;
        for (int jj = 0; jj < 3; ++jj) {
            int j = jj * 64 + l;
            float c = 0.f;
            for (int d = 0; d < 64; ++d) c += vb[d] * gwih[j * 128 + 64 + d];
            cvec[j] = c;
        }
    } else if (blk < 257) {
        int d = blk - 193;
        headT[d * 64 + l] = hw[l * 64 + d];
    } else if (blk < 321) {
        // zero the slot array (256 steps x 256 blocks x u64)
        float* z = ws + OFF_SLOTS;
        int base = (blk - 257) * 2048;
        for (int i = base + l; i < base + 2048; i += 64) z[i] = 0.f;
    } else {
        // bf16 conversion of memory: one row per block
        int r = blk - 321;
        const float* src = memory + (size_t)r * 16384;
        unsigned short* dst = (unsigned short*)(ws + OFF_MBF) + (size_t)r * 16384;
        for (int i = 0; i < 64; ++i) {
            int idx = i * 256 + l * 4;
            float4 v = *(const float4*)(src + idx);
            ushort4 o;
            o.x = f2bf(v.x); o.y = f2bf(v.y); o.z = f2bf(v.z); o.w = f2bf(v.w);
            *(ushort4*)(dst + idx) = o;
        }
    }
}

// ---------------- persistent kernel: 4 rows/block ----------------
__global__ __launch_bounds__(256, 1) void persist_k(
    const int* __restrict__ seq, const float* __restrict__ memory,
    const float* __restrict__ gwhh, const float* __restrict__ gbhh,
    const float* __restrict__ lwih, const float* __restrict__ lwhh,
    const float* __restrict__ lbih, const float* __restrict__ lbhh,
    const float* __restrict__ tw, const float* __restrict__ tb,
    const float* __restrict__ hb, float* __restrict__ ws,
    float* __restrict__ out, int use_bf16)
{
    int tid = threadIdx.x;
    int w = tid >> 6, l = tid & 63;
    int b = blockIdx.x;
    int r = b * 4 + w;            // batch row owned by this wave

    const float* tokproj = ws + OFF_TOKPROJ;
    const float* A_ws = ws + OFF_A;
    const float* avec = ws + OFF_AVEC;
    const float* Gsrc = ws + OFF_G;
    const float* cvec = ws + OFF_CVEC;
    const float* headT = ws + OFF_HEADT;
    unsigned long long* slots = (unsigned long long*)(ws + OFF_SLOTS);

    __shared__ float mch[4][32][65];
    __shared__ float G_lds[12288];
    __shared__ float wlT[8192];
    __shared__ float lwhhT_s[32][128];
    __shared__ float hs[4][64], us[4][64], qs[4][64], wsm_s[4][32];
    __shared__ float PX[4][4][128];
    __shared__ int toks[4][256];
    __shared__ unsigned long long probq[4];
    __shared__ int flagLds;

    // ---- one-time cooperative staging ----
    for (int i = tid; i < 12288; i += TPB) G_lds[i] = Gsrc[i];
    for (int i = tid; i < 8192; i += TPB) {
        int d = i >> 7, j = i & 127;
        wlT[i] = lwih[j * 64 + d];                 // wlT[d*128 + j]
    }
    for (int i = tid; i < 4096; i += TPB) {
        int j = i >> 5, d = i & 31;
        lwhhT_s[d][j] = lwhh[i];                   // lwhh[j*32 + d]
    }
    for (int k = 0; k < 4; ++k) toks[w][k * 64 + l] = seq[r * 256 + k * 64 + l];
    if (tid == 0) flagLds = 0;

    // gwhh rows {l, 64+l, 128+l} -> registers, coalesced LDS bounce per wave
    float whh0[64], whh1[64], whh2[64];
    for (int c = 0; c < 6; ++c) {
        for (int r2 = 0; r2 < 32; ++r2) mch[w][r2][l & 31] = gwhh[(c * 32 + r2) * 64 + l];
        // NOTE: need full 64 cols; do it as before with [64]-wide rows:
        // (mch row is 65 floats wide; staging 64 cols)
        // -- rewritten below properly --
        break;
    }
    // proper staging (wave-local, barrier-free):
    for (int c = 0; c < 6; ++c) {
        for (int r2 = 0; r2 < 32; ++r2) mch[w][r2][l] = gwhh[(c * 32 + r2) * 64 + l];
        if ((l >> 5) == c) {
            #pragma unroll
            for (int d = 0; d < 64; ++d) whh0[d] = mch[w][l & 31][d];
        }
        if ((l >> 5) == c - 2) {
            #pragma unroll
            for (int d = 0; d < 64; ++d) whh1[d] = mch[w][l & 31][d];
        }
        if ((l >> 5) == c - 4) {
            #pragma unroll
            for (int d = 0; d < 64; ++d) whh2[d] = mch[w][l & 31][d];
        }
    }

    float g0b = gbhh[l], g1b = gbhh[64 + l], g2b = gbhh[128 + l];
    float lb0 = lbih[l] + lbhh[l], lb1 = lbih[64 + l] + lbhh[64 + l];
    float avr = avec[l];
    float cv0 = cvec[l], cv1 = cvec[64 + l], cv2 = cvec[128 + l];
    float twr = (l < 32) ? tw[l] : 0.f;
    float tb0 = tb[0];
    float h = 0.f;
    hs[w][l] = 0.f;
    int cnt = 0;
    bool brk = false;
    const float* mrow = memory + (size_t)r * 16384;
    const unsigned short* mbf = (const unsigned short*)(ws + OFF_MBF) + (size_t)r * 16384;
    __syncthreads();

    for (int t = 0; t < 256; ++t) {
        // GRU h-projection (depends only on h_{t-1})
        float gh0 = g0b, gh1 = g1b, gh2 = g2b;
        #pragma unroll
        for (int d = 0; d < 64; ++d) {
            float s = hs[w][d];
            gh0 += s * whh0[d]; gh1 += s * whh1[d]; gh2 += s * whh2[d];
        }
        int tok = toks[w][t];
        const float* tp = tokproj + tok * 192;
        float gi0 = tp[l], gi1 = tp[64 + l], gi2 = tp[128 + l];

        bool flag = false;
        if (t >= 4) {
            // ---- speculative attention on h_{t-1} (wave-local, barrier-free) ----
            float qk = avr;
            #pragma unroll
            for (int d = 0; d < 64; ++d) qk += hs[w][d] * A_ws[d * 64 + l];
            qs[w][l] = qk;
            float Mx = -1e30f, D = 0.f, u = 0.f;
            for (int c = 0; c < 8; ++c) {
                if (use_bf16) {
                    #pragma unroll
                    for (int it = 0; it < 16; ++it) {
                        int sl2 = it * 2 + (l >> 5);
                        int m = l & 31;
                        unsigned int v = *(const unsigned int*)(mbf + (size_t)(c * 32 + sl2) * 64 + m * 2);
                        mch[w][sl2][m * 2]     = __uint_as_float(v << 16);
                        mch[w][sl2][m * 2 + 1] = __uint_as_float(v & 0xffff0000u);
                    }
                } else {
                    for (int r2 = 0; r2 < 32; ++r2) mch[w][r2][l] = mrow[(size_t)(c * 32 + r2) * 64 + l];
                }
                int m = l & 31, dh = (l >> 5) * 32;
                float s = 0.f;
                #pragma unroll
                for (int dd = 0; dd < 32; ++dd) s += qs[w][dh + dd] * mch[w][m][dh + dd];
                s += __shfl_xor(s, 32);
                float cm = s;
                cm = fmaxf(cm, __shfl_xor(cm, 16)); cm = fmaxf(cm, __shfl_xor(cm, 8));
                cm = fmaxf(cm, __shfl_xor(cm, 4));  cm = fmaxf(cm, __shfl_xor(cm, 2));
                cm = fmaxf(cm, __shfl_xor(cm, 1));
                float newM = fmaxf(Mx, cm);
                float fac = expf(Mx - newM), wv = expf(s - newM);
                if (l < 32) wsm_s[w][l] = wv;
                float sw = wv;
                sw += __shfl_xor(sw, 16); sw += __shfl_xor(sw, 8);
                sw += __shfl_xor(sw, 4);  sw += __shfl_xor(sw, 2);
                sw += __shfl_xor(sw, 1);
                D = D * fac + sw; u *= fac;
                #pragma unroll
                for (int m2 = 0; m2 < 32; ++m2) u += wsm_s[w][m2] * mch[w][m2][l];
                Mx = newM;
            }
            us[w][l] = u / D;

            // ---- poll flag(t-1): marks first, sum once complete ----
            if (w == 0) {
                const unsigned long long* sl = slots + (size_t)(t - 1) * 256;
                unsigned long long v0 = 0, v1 = 0, v2 = 0, v3 = 0;
                int it = 0, ok = 1;
                if (!brk) {
                    for (;;) {
                        v0 = __hip_atomic_load(sl + l, __ATOMIC_RELAXED, __HIP_MEMORY_SCOPE_AGENT);
                        v1 = __hip_atomic_load(sl + 64 + l, __ATOMIC_RELAXED, __HIP_MEMORY_SCOPE_AGENT);
                        v2 = __hip_atomic_load(sl + 128 + l, __ATOMIC_RELAXED, __HIP_MEMORY_SCOPE_AGENT);
                        v3 = __hip_atomic_load(sl + 192 + l, __ATOMIC_RELAXED, __HIP_MEMORY_SCOPE_AGENT);
                        bool have = (((v0 & v1 & v2 & v3) >> 44) & 1ULL) != 0ULL;
                        if (__all(have)) break;
                        if (++it > (1 << 15)) { ok = 0; brk = true; break; }
                        __builtin_amdgcn_s_sleep(1);
                    }
                } else ok = 0;
                unsigned long long tot = v0 + v1 + v2 + v3;
                #pragma unroll
                for (int o = 32; o; o >>= 1) tot += __shfl_xor(tot, o);
                int f = ok && ((tot & MASK44) > THRESH);
                cnt += f;                          // wave-uniform on wave 0
                if (l == 0) flagLds = f;
            }
            __syncthreads();                       // B1: flag broadcast
            flag = (flagLds != 0);
        }

        if (flag) {
            gi0 += cv0; gi1 += cv1; gi2 += cv2;
            #pragma unroll
            for (int e = 0; e < 64; ++e) {
                float s2 = us[w][e];
                gi0 += s2 * G_lds[e * 192 + l];
                gi1 += s2 * G_lds[e * 192 + 64 + l];
                gi2 += s2 * G_lds[e * 192 + 128 + l];
            }
        }

        // finish GRU (hs is wave-local)
        float r_ = sigf(gi0 + gh0), z_ = sigf(gi1 + gh1);
        float n_ = tanhf(gi2 + r_ * gh2);
        float hn = (1.f - z_) * n_ + z_ * h;
        h = hn;
        hs[w][l] = hn;

        // trigger-LSTM input projection for h_t (reused 4 steps)
        float p0 = lb0, p1 = lb1;
        #pragma unroll
        for (int d = 0; d < 64; ++d) {
            float s = hs[w][d];
            p0 += s * wlT[d * 128 + l];
            p1 += s * wlT[d * 128 + 64 + l];
        }
        PX[w][t & 3][l] = p0; PX[w][t & 3][64 + l] = p1;   // same-lane readback only

        if (t >= 3) {
            float hh = 0.f, cc = 0.f;                       // lanes 0..31 hold state
            #pragma unroll
            for (int k = 0; k < 4; ++k) {
                float q0, q1;
                if (k == 3) { q0 = p0; q1 = p1; }
                else { int sl2 = (t - 3 + k) & 3; q0 = PX[w][sl2][l]; q1 = PX[w][sl2][64 + l]; }
                if (k) {
                    #pragma unroll
                    for (int d = 0; d < 32; ++d) {
                        float s = __shfl(hh, d);            // broadcast lane d's state
                        q0 += s * lwhhT_s[d][l];
                        q1 += s * lwhhT_s[d][64 + l];
                    }
                }
                float f_ = __shfl(q0, l + 32), o_ = __shfl(q1, l + 32);
                float ig = sigf(q0), ff = sigf(f_), gg = tanhf(q1), oo = sigf(o_);
                float ncc = ff * cc + ig * gg;
                float nhh = oo * tanhf(ncc);
                if (l < 32) { cc = ncc; hh = nhh; }
            }
            float pp = (l < 32) ? hh * twr : 0.f;
            #pragma unroll
            for (int o = 32; o; o >>= 1) pp += __shfl_xor(pp, o);
            if (l == 0) {
                float prob = sigf(pp + tb0);
                probq[w] = (unsigned long long)llrint((double)prob * 1073741824.0);
            }
            __syncthreads();                       // B2: probq gather
            if (tid == 0) {
                unsigned long long sv = probq[0] + probq[1] + probq[2] + probq[3] + MARK;
                __hip_atomic_store(&slots[(size_t)t * 256 + b], sv,
                                   __ATOMIC_RELAXED, __HIP_MEMORY_SCOPE_AGENT);
            }
        }
    }

    // epilogue: logits
    float sL = hb[l];
    #pragma unroll
    for (int d = 0; d < 64; ++d) sL += hs[w][d] * headT[d * 64 + l];
    out[r * 64 + l] = sL;

    // read_rate: block 0 wave 0 also needs the final flag (t=255)
    if (b == 0 && w == 0) {
        const unsigned long long* sl = slots + (size_t)255 * 256;
        unsigned long long v0 = 0, v1 = 0, v2 = 0, v3 = 0;
        int it = 0, ok = 1;
        if (!brk) {
            for (;;) {
                v0 = __hip_atomic_load(sl + l, __ATOMIC_RELAXED, __HIP_MEMORY_SCOPE_AGENT);
                v1 = __hip_atomic_load(sl + 64 + l, __ATOMIC_RELAXED, __HIP_MEMORY_SCOPE_AGENT);
                v2 = __hip_atomic_load(sl + 128 + l, __ATOMIC_RELAXED, __HIP_MEMORY_SCOPE_AGENT);
                v3 = __hip_atomic_load(sl + 192 + l, __ATOMIC_RELAXED, __HIP_MEMORY_SCOPE_AGENT);
                bool have = (((v0 & v1 & v2 & v3) >> 44) & 1ULL) != 0ULL;
                if (__all(have)) break;
                if (++it > (1 << 15)) { ok = 0; brk = true; break; }
                __builtin_amdgcn_s_sleep(1);
            }
        } else ok = 0;
        unsigned long long tot = v0 + v1 + v2 + v3;
        #pragma unroll
        for (int o = 32; o; o >>= 1) tot += __shfl_xor(tot, o);
        cnt += (ok && ((tot & MASK44) > THRESH)) ? 1 : 0;
        if (l == 0) out[65536] = brk ? -1234.0f : (float)cnt / 256.f;
    }
}

extern "C" void kernel_launch(void* const* d_in, const int* in_sizes, int n_in,
                              void* d_out, int out_size, void* d_ws, size_t ws_size,
                              hipStream_t stream)
{
    const int*   seq    = (const int*)d_in[0];
    const float* memory = (const float*)d_in[1];
    const float* embed  = (const float*)d_in[2];
    const float* gwih   = (const float*)d_in[3];
    const float* gwhh   = (const float*)d_in[4];
    const float* gbih   = (const float*)d_in[5];
    const float* gbhh   = (const float*)d_in[6];
    const float* qw     = (const float*)d_in[7];
    const float* qb     = (const float*)d_in[8];
    const float* kw     = (const float*)d_in[9];
    // d_in[10] = k_b : cancels in softmax, unused
    const float* vw     = (const float*)d_in[11];
    const float* vb     = (const float*)d_in[12];
    const float* lwih   = (const float*)d_in[13];
    const float* lwhh   = (const float*)d_in[14];
    const float* lbih   = (const float*)d_in[15];
    const float* lbhh   = (const float*)d_in[16];
    const float* tw     = (const float*)d_in[17];
    const float* tb     = (const float*)d_in[18];
    const float* hw     = (const float*)d_in[19];
    const float* hb     = (const float*)d_in[20];
    float* ws = (float*)d_ws;
    float* out = (float*)d_out;

    int use_bf16 = (ws_size >= WS_NEED_BF16) ? 1 : 0;
    int prep_blocks = use_bf16 ? (321 + 1024) : 321;

    prep_k<<<prep_blocks, 64, 0, stream>>>(embed, gwih, gbih, qw, qb, kw, vw,
                                           vb, hw, memory, ws);
    persist_k<<<NBLK, TPB, 0, stream>>>(seq, memory, gwhh, gbhh, lwih, lwhh,
                                        lbih, lbhh, tw, tb, hb, ws, out, use_bf16);
}

// Round 7
// 6393.485 us; speedup vs baseline: 2.0075x; 2.0075x over previous
//
#include <hip/hip_runtime.h>
#include <math.h>

#define NBLK 256
#define TPB  320            // 4 worker waves + 1 (reducer on block 0, exits elsewhere)
#define RGATE 24            // max run-ahead (ring depth 32, need tc-2 intact)
#define SPIN_BOUND (1 << 18)

// ws float offsets
#define OFF_TOKPROJ 0        // 64*192 = 12288
#define OFF_A       12288    // 64*64
#define OFF_AVEC    16384    // 64
#define OFF_G       16448    // 64*192
#define OFF_CVEC    28736    // 192
#define OFF_HEADT   28928    // 64*64
#define OFF_FLAGS   33024    // 256 u64 = 512 f
#define OFF_SLOTS   33536    // 256*1024 u64 = 524288 f
#define ZERO_BASE   33024
#define ZERO_LEN    (512 + 524288)

#define MASK44 ((1ULL << 44) - 1)
#define THRESH (512ULL << 30)   // mean > 0.5  <=>  sum(prob*2^30) > 512*2^30

__device__ __forceinline__ float sigf(float x) { return 1.f / (1.f + expf(-x)); }

// ---------------- prep: fused tables, zero slots+flags ----------------
__global__ __launch_bounds__(64) void prep_k(
    const float* __restrict__ embed, const float* __restrict__ gwih,
    const float* __restrict__ gbih, const float* __restrict__ qw,
    const float* __restrict__ qb, const float* __restrict__ kw,
    const float* __restrict__ vw, const float* __restrict__ vb,
    const float* __restrict__ hw, float* __restrict__ ws)
{
    int blk = blockIdx.x, l = threadIdx.x;
    float* tokproj = ws + OFF_TOKPROJ;
    float* A = ws + OFF_A;
    float* avec = ws + OFF_AVEC;
    float* G = ws + OFF_G;
    float* cvec = ws + OFF_CVEC;
    float* headT = ws + OFF_HEADT;

    if (blk < 64) {
        int v = blk;
        for (int j = l; j < 192; j += 64) {
            float s = gbih[j];
            for (int d = 0; d < 64; ++d) s += embed[v * 64 + d] * gwih[j * 128 + d];
            tokproj[v * 192 + j] = s;
        }
    } else if (blk < 128) {
        int d = blk - 64;
        float s = 0.f;
        for (int e = 0; e < 64; ++e) s += qw[e * 64 + d] * kw[e * 64 + l];
        A[d * 64 + l] = s * 0.125f;   // 1/sqrt(64)
    } else if (blk < 192) {
        int e = blk - 128;
        for (int jj = 0; jj < 3; ++jj) {
            int j = jj * 64 + l;
            float s = 0.f;
            for (int d = 0; d < 64; ++d) s += vw[d * 64 + e] * gwih[j * 128 + 64 + d];
            G[e * 192 + j] = s;
        }
    } else if (blk == 192) {
        float s = 0.f;
        for (int e = 0; e < 64; ++e) s += qb[e] * kw[e * 64 + l];
        avec[l] = s * 0.125f;
        for (int jj = 0; jj < 3; ++jj) {
            int j = jj * 64 + l;
            float c = 0.f;
            for (int d = 0; d < 64; ++d) c += vb[d] * gwih[j * 128 + 64 + d];
            cvec[j] = c;
        }
    } else if (blk < 257) {
        int d = blk - 193;
        headT[d * 64 + l] = hw[l * 64 + d];
    } else {
        int base = ZERO_BASE + (blk - 257) * 4096;
        int end = ZERO_BASE + ZERO_LEN;
        for (int i = base + l; i < base + 4096; i += 64)
            if (i < end) ws[i] = 0.f;
    }
}

// ---------------- persistent kernel: speculative flag-0 execution ----------
__global__ __launch_bounds__(TPB, 1) void persist_k(
    const int* __restrict__ seq, const float* __restrict__ memory,
    const float* __restrict__ gwhh, const float* __restrict__ gbhh,
    const float* __restrict__ lwih, const float* __restrict__ lwhh,
    const float* __restrict__ lbih, const float* __restrict__ lbhh,
    const float* __restrict__ tw, const float* __restrict__ tb,
    const float* __restrict__ hb, float* __restrict__ ws,
    float* __restrict__ out)
{
    int tid = threadIdx.x;
    int wv = tid >> 6, l = tid & 63;
    int b = blockIdx.x;

    const float* tokproj = ws + OFF_TOKPROJ;
    const float* A_ws = ws + OFF_A;
    const float* avec = ws + OFF_AVEC;
    const float* Gw = ws + OFF_G;
    const float* cvec = ws + OFF_CVEC;
    const float* headT = ws + OFF_HEADT;
    unsigned long long* slots = (unsigned long long*)(ws + OFF_SLOTS);
    unsigned long long* flags = (unsigned long long*)(ws + OFF_FLAGS);

    __shared__ float ring[4][32][64];     // h history per wave (rollback checkpoints)
    __shared__ float mch[4][32][65];
    __shared__ float wlT[8192];           // lstm_wih^T [d*128 + j]
    __shared__ float lwhhT_s[32][128];
    __shared__ float PX[4][4][128];
    __shared__ float us[4][64], qsh[4][64], wsm_s[4][32];
    __shared__ int toks[4][256];

    // ---- one-time cooperative staging (only cross-wave LDS; single barrier) ----
    for (int i = tid; i < 8192; i += TPB) {
        int d = i >> 7, j = i & 127;
        wlT[i] = lwih[j * 64 + d];
    }
    for (int i = tid; i < 4096; i += TPB) {
        int j = i >> 5, d = i & 31;
        lwhhT_s[d][j] = lwhh[i];
    }
    __syncthreads();   // the ONLY block-wide barrier

    // ================= REDUCER (wave 4 of block 0) =================
    if (wv == 4) {
        if (b != 0) return;
        int ep = 0, cnt = 0;
        bool okr = true;
        for (int ti = 3; ti < 256; ++ti) {
            unsigned long long sum = 0;
            int spin = 0;
            for (;;) {
                bool all16 = true;
                sum = 0;
                #pragma unroll
                for (int k = 0; k < 16; ++k) {
                    unsigned long long v = __hip_atomic_load(
                        &slots[(size_t)ti * 1024 + k * 64 + l],
                        __ATOMIC_RELAXED, __HIP_MEMORY_SCOPE_AGENT);
                    all16 &= ((int)(v >> 44) == 2 * ep + 1);
                    sum += v & MASK44;
                }
                if (__all(all16)) break;
                if (++spin > SPIN_BOUND) { okr = false; break; }
                __builtin_amdgcn_s_sleep(1);
            }
            if (!okr) break;
            #pragma unroll
            for (int o = 32; o; o >>= 1) sum += __shfl_xor(sum, o);
            int dec = (sum & MASK44) > THRESH ? 1 : 0;
            if (l == 0)
                __hip_atomic_store(&flags[ti], (unsigned long long)(1 | (dec << 1)),
                                   __ATOMIC_RELAXED, __HIP_MEMORY_SCOPE_AGENT);
            cnt += dec;
            ep += dec;
        }
        if (l == 0) out[65536] = okr ? (float)cnt / 256.f : -1234.f;
        return;
    }

    // ================= WORKER WAVES (4 rows/block, wave-local) =================
    int r = b * 4 + wv;
    for (int k = 0; k < 4; ++k) toks[wv][k * 64 + l] = seq[r * 256 + k * 64 + l];

    // gwhh rows {l, 64+l, 128+l} -> registers via wave-local LDS bounce
    float whh0[64], whh1[64], whh2[64];
    for (int c = 0; c < 6; ++c) {
        for (int r2 = 0; r2 < 32; ++r2) mch[wv][r2][l] = gwhh[(c * 32 + r2) * 64 + l];
        if ((l >> 5) == c) {
            #pragma unroll
            for (int d = 0; d < 64; ++d) whh0[d] = mch[wv][l & 31][d];
        }
        if ((l >> 5) == c - 2) {
            #pragma unroll
            for (int d = 0; d < 64; ++d) whh1[d] = mch[wv][l & 31][d];
        }
        if ((l >> 5) == c - 4) {
            #pragma unroll
            for (int d = 0; d < 64; ++d) whh2[d] = mch[wv][l & 31][d];
        }
    }

    float g0b = gbhh[l], g1b = gbhh[64 + l], g2b = gbhh[128 + l];
    float lb0 = lbih[l] + lbhh[l], lb1 = lbih[64 + l] + lbhh[64 + l];
    float avr = avec[l];
    float cv0 = cvec[l], cv1 = cvec[64 + l], cv2 = cvec[128 + l];
    float twr = (l < 32) ? tw[l] : 0.f;
    float tb0 = tb[0];
    const float* mrow = memory + (size_t)r * 16384;

    int t = 0, tf = 3, ep = 0;
    bool fire = false, okf = true;
    ring[wv][31][l] = 0.f;               // h_{-1} = 0  ((0-1)&31 == 31)

    while (okf) {
        if (t <= 255) {
            // ----- speculative compute of step t (assume pending flags = 0) -----
            int ps = (t + 31) & 31;
            float gh0 = g0b, gh1 = g1b, gh2 = g2b;
            #pragma unroll
            for (int d = 0; d < 64; ++d) {
                float s = ring[wv][ps][d];
                gh0 += s * whh0[d]; gh1 += s * whh1[d]; gh2 += s * whh2[d];
            }
            const float* tp = tokproj + toks[wv][t] * 192;
            float gi0 = tp[l], gi1 = tp[64 + l], gi2 = tp[128 + l];
            if (fire) {                   // confirmed fire at t-1: apply retrieved
                fire = false;
                gi0 += cv0; gi1 += cv1; gi2 += cv2;
                for (int e = 0; e < 64; ++e) {
                    float s2 = us[wv][e];
                    gi0 += s2 * Gw[e * 192 + l];
                    gi1 += s2 * Gw[e * 192 + 64 + l];
                    gi2 += s2 * Gw[e * 192 + 128 + l];
                }
            }
            float hp = ring[wv][ps][l];
            float r_ = sigf(gi0 + gh0), z_ = sigf(gi1 + gh1);
            float n_ = tanhf(gi2 + r_ * gh2);
            float hn = (1.f - z_) * n_ + z_ * hp;
            ring[wv][t & 31][l] = hn;

            // trigger-LSTM input projection
            float p0 = lb0, p1 = lb1;
            #pragma unroll
            for (int d = 0; d < 64; ++d) {
                float s = ring[wv][t & 31][d];
                p0 += s * wlT[d * 128 + l];
                p1 += s * wlT[d * 128 + 64 + l];
            }
            PX[wv][t & 3][l] = p0; PX[wv][t & 3][64 + l] = p1;

            if (t >= 3) {
                float hh = 0.f, cc = 0.f;    // lanes 0..31 hold LSTM state
                #pragma unroll
                for (int k = 0; k < 4; ++k) {
                    float q0, q1;
                    if (k == 3) { q0 = p0; q1 = p1; }
                    else { int s2 = (t - 3 + k) & 3; q0 = PX[wv][s2][l]; q1 = PX[wv][s2][64 + l]; }
                    if (k) {
                        #pragma unroll
                        for (int d = 0; d < 32; ++d) {
                            float s = __shfl(hh, d);
                            q0 += s * lwhhT_s[d][l];
                            q1 += s * lwhhT_s[d][64 + l];
                        }
                    }
                    float f_ = __shfl(q0, l + 32), o_ = __shfl(q1, l + 32);
                    float ig = sigf(q0), ff = sigf(f_), gg = tanhf(q1), oo = sigf(o_);
                    float ncc = ff * cc + ig * gg;
                    float nhh = oo * tanhf(ncc);
                    if (l < 32) { cc = ncc; hh = nhh; }
                }
                float pp = (l < 32) ? hh * twr : 0.f;
                #pragma unroll
                for (int o = 32; o; o >>= 1) pp += __shfl_xor(pp, o);
                if (l == 0) {
                    float prob = sigf(pp + tb0);
                    unsigned long long q = (unsigned long long)llrint((double)prob * 1073741824.0);
                    __hip_atomic_store(&slots[(size_t)t * 1024 + r],
                                       ((unsigned long long)(2 * ep + 1) << 44) | q,
                                       __ATOMIC_RELAXED, __HIP_MEMORY_SCOPE_AGENT);
                }
            }
            ++t;
        }

        // ----- consume confirmed flags (non-blocking unless gated) -----
        int spin = 0;
        for (;;) {
            if (tf >= 256) break;
            bool gated = (t > 255) || (t > tf + RGATE);
            unsigned long long fv = 0;
            if (l == 0)
                fv = __hip_atomic_load(&flags[tf], __ATOMIC_RELAXED, __HIP_MEMORY_SCOPE_AGENT);
            fv = __shfl(fv, 0);          // wave-uniform broadcast
            if (fv & 1ULL) {
                if (((fv >> 1) & 1ULL) == 0ULL) { ++tf; continue; }
                // ---- FIRE at tc = tf : rollback + attention (exact fp32) ----
                int tc = tf;
                {
                    float qk = avr;
                    #pragma unroll
                    for (int d = 0; d < 64; ++d) qk += ring[wv][tc & 31][d] * A_ws[d * 64 + l];
                    qsh[wv][l] = qk;
                    float Mx = -1e30f, D = 0.f, u = 0.f;
                    for (int c = 0; c < 8; ++c) {
                        for (int r2 = 0; r2 < 32; ++r2)
                            mch[wv][r2][l] = mrow[(size_t)(c * 32 + r2) * 64 + l];
                        int m = l & 31, dh = (l >> 5) * 32;
                        float s = 0.f;
                        #pragma unroll
                        for (int dd = 0; dd < 32; ++dd) s += qsh[wv][dh + dd] * mch[wv][m][dh + dd];
                        s += __shfl_xor(s, 32);
                        float cm = s;
                        cm = fmaxf(cm, __shfl_xor(cm, 16)); cm = fmaxf(cm, __shfl_xor(cm, 8));
                        cm = fmaxf(cm, __shfl_xor(cm, 4));  cm = fmaxf(cm, __shfl_xor(cm, 2));
                        cm = fmaxf(cm, __shfl_xor(cm, 1));
                        float newM = fmaxf(Mx, cm);
                        float fac = expf(Mx - newM), wvv = expf(s - newM);
                        if (l < 32) wsm_s[wv][l] = wvv;
                        float sw = wvv;
                        sw += __shfl_xor(sw, 16); sw += __shfl_xor(sw, 8);
                        sw += __shfl_xor(sw, 4);  sw += __shfl_xor(sw, 2);
                        sw += __shfl_xor(sw, 1);
                        D = D * fac + sw; u *= fac;
                        #pragma unroll
                        for (int m2 = 0; m2 < 32; ++m2) u += wsm_s[wv][m2] * mch[wv][m2][l];
                        Mx = newM;
                    }
                    us[wv][l] = u / D;
                }
                // restore PX ring for hist steps tc-2..tc from the h ring
                for (int j = tc - 2; j <= tc; ++j) {
                    float q0 = lb0, q1 = lb1;
                    #pragma unroll
                    for (int d = 0; d < 64; ++d) {
                        float s = ring[wv][j & 31][d];
                        q0 += s * wlT[d * 128 + l];
                        q1 += s * wlT[d * 128 + 64 + l];
                    }
                    PX[wv][j & 3][l] = q0; PX[wv][j & 3][64 + l] = q1;
                }
                ++ep; tf = tc + 1; t = tc + 1; fire = true;
                break;                   // resume compute at t = tc+1
            } else {
                if (!gated) break;
                if (++spin > SPIN_BOUND) { okf = false; break; }
                __builtin_amdgcn_s_sleep(1);
            }
        }
        if (t > 255 && tf >= 256) break;
    }

    // epilogue: logits from confirmed h_255 (ring[255&31] == ring[31])
    float sL = hb[l];
    #pragma unroll
    for (int d = 0; d < 64; ++d) sL += ring[wv][31][d] * headT[d * 64 + l];
    out[r * 64 + l] = sL;
}

extern "C" void kernel_launch(void* const* d_in, const int* in_sizes, int n_in,
                              void* d_out, int out_size, void* d_ws, size_t ws_size,
                              hipStream_t stream)
{
    const int*   seq    = (const int*)d_in[0];
    const float* memory = (const float*)d_in[1];
    const float* embed  = (const float*)d_in[2];
    const float* gwih   = (const float*)d_in[3];
    const float* gwhh   = (const float*)d_in[4];
    const float* gbih   = (const float*)d_in[5];
    const float* gbhh   = (const float*)d_in[6];
    const float* qw     = (const float*)d_in[7];
    const float* qb     = (const float*)d_in[8];
    const float* kw     = (const float*)d_in[9];
    // d_in[10] = k_b : cancels in softmax, unused
    const float* vw     = (const float*)d_in[11];
    const float* vb     = (const float*)d_in[12];
    const float* lwih   = (const float*)d_in[13];
    const float* lwhh   = (const float*)d_in[14];
    const float* lbih   = (const float*)d_in[15];
    const float* lbhh   = (const float*)d_in[16];
    const float* tw     = (const float*)d_in[17];
    const float* tb     = (const float*)d_in[18];
    const float* hw     = (const float*)d_in[19];
    const float* hb     = (const float*)d_in[20];
    float* ws = (float*)d_ws;
    float* out = (float*)d_out;

    prep_k<<<386, 64, 0, stream>>>(embed, gwih, gbih, qw, qb, kw, vw, vb, hw, ws);
    persist_k<<<NBLK, TPB, 0, stream>>>(seq, memory, gwhh, gbhh, lwih, lwhh,
                                        lbih, lbhh, tw, tb, hb, ws, out);
}

// Round 8
// 1883.055 us; speedup vs baseline: 6.8161x; 3.3953x over previous
//
#include <hip/hip_runtime.h>
#include <math.h>

#define TPB  256
#define NWB  256              // worker blocks; block NWB is the verifier
#define SPIN_BOUND (1 << 18)

// ws float offsets
#define OFF_TOKPROJ 0         // 64*192
#define OFF_A       12288     // 64*64
#define OFF_AVEC    16384     // 64
#define OFF_G       16448     // 64*192
#define OFF_CVEC    28736     // 192
#define OFF_HEADT   28928     // 64*64
#define OFF_FLAGS   33024     // 256 u64
#define OFF_VERDICT 33536     // 1 u64
#define OFF_SLOTS   33600     // 256*1024 u64
#define ZERO_BASE   33024
#define ZERO_END    (33600 + 524288)

#define MASK44 ((1ULL << 44) - 1)
#define THRESH (512ULL << 30)  // mean > 0.5  <=>  sum(prob*2^30) > 512*2^30

__device__ __forceinline__ float sigf(float x) { return 1.f / (1.f + expf(-x)); }

// ---------------- prep: fused tables, zero slots/flags/verdict ----------------
__global__ __launch_bounds__(64) void prep_k(
    const float* __restrict__ embed, const float* __restrict__ gwih,
    const float* __restrict__ gbih, const float* __restrict__ qw,
    const float* __restrict__ qb, const float* __restrict__ kw,
    const float* __restrict__ vw, const float* __restrict__ vb,
    const float* __restrict__ hw, float* __restrict__ ws)
{
    int blk = blockIdx.x, l = threadIdx.x;
    float* tokproj = ws + OFF_TOKPROJ;
    float* A = ws + OFF_A;
    float* avec = ws + OFF_AVEC;
    float* G = ws + OFF_G;
    float* cvec = ws + OFF_CVEC;
    float* headT = ws + OFF_HEADT;

    if (blk < 64) {
        int v = blk;
        for (int j = l; j < 192; j += 64) {
            float s = gbih[j];
            for (int d = 0; d < 64; ++d) s += embed[v * 64 + d] * gwih[j * 128 + d];
            tokproj[v * 192 + j] = s;
        }
    } else if (blk < 128) {
        int d = blk - 64;
        float s = 0.f;
        for (int e = 0; e < 64; ++e) s += qw[e * 64 + d] * kw[e * 64 + l];
        A[d * 64 + l] = s * 0.125f;   // 1/sqrt(64)
    } else if (blk < 192) {
        int e = blk - 128;
        for (int jj = 0; jj < 3; ++jj) {
            int j = jj * 64 + l;
            float s = 0.f;
            for (int d = 0; d < 64; ++d) s += vw[d * 64 + e] * gwih[j * 128 + 64 + d];
            G[e * 192 + j] = s;
        }
    } else if (blk == 192) {
        float s = 0.f;
        for (int e = 0; e < 64; ++e) s += qb[e] * kw[e * 64 + l];
        avec[l] = s * 0.125f;
        for (int jj = 0; jj < 3; ++jj) {
            int j = jj * 64 + l;
            float c = 0.f;
            for (int d = 0; d < 64; ++d) c += vb[d] * gwih[j * 128 + 64 + d];
            cvec[j] = c;
        }
    } else if (blk < 257) {
        int d = blk - 193;
        headT[d * 64 + l] = hw[l * 64 + d];
    } else {
        int base = ZERO_BASE + (blk - 257) * 4096;
        for (int i = base + l; i < base + 4096; i += 64)
            if (i < ZERO_END) ws[i] = 0.f;
    }
}

// ---------------- persistent kernel: speculate, verify concurrently ----------
__global__ __launch_bounds__(TPB, 2) void persist_k(
    const int* __restrict__ seq, const float* __restrict__ memory,
    const float* __restrict__ gwhh, const float* __restrict__ gbhh,
    const float* __restrict__ lwih, const float* __restrict__ lwhh,
    const float* __restrict__ lbih, const float* __restrict__ lbhh,
    const float* __restrict__ tw, const float* __restrict__ tb,
    const float* __restrict__ hb, float* __restrict__ ws,
    float* __restrict__ out)
{
    int tid = threadIdx.x, wv = tid >> 6, l = tid & 63, b = blockIdx.x;

    const float* tokproj = ws + OFF_TOKPROJ;
    const float* A_ws = ws + OFF_A;
    const float* avec = ws + OFF_AVEC;
    const float* Gw = ws + OFF_G;
    const float* cvec = ws + OFF_CVEC;
    const float* headT = ws + OFF_HEADT;
    unsigned long long* flags = (unsigned long long*)(ws + OFF_FLAGS);
    unsigned long long* verdict = (unsigned long long*)(ws + OFF_VERDICT);
    unsigned long long* slots = (unsigned long long*)(ws + OFF_SLOTS);

    __shared__ float ring[4][2][64];     // h_{t-1}, h_t per wave
    __shared__ float wlI[8192];          // lstm W_ih interleaved per-lane float4 pairs
    __shared__ float whh2I[4096];        // GRU n-gate W_hh interleaved
    __shared__ float lwhI[4096];         // lstm W_hh interleaved
    __shared__ float PX[4][4][128];      // trigger input-proj history (+ staging scratch)
    __shared__ int toks[4][256];
    __shared__ int firstf[4];

    // ---- cooperative staging ----
    for (int i = tid; i < 8192; i += TPB) {
        int d4 = i >> 9, rem = i & 511, l2 = rem >> 3, jj = rem & 7, j = jj >> 1, which = jj & 1;
        wlI[i] = lwih[(which ? 64 + l2 : l2) * 64 + d4 * 4 + j];
    }
    for (int i = tid; i < 4096; i += TPB) {
        int d4 = i >> 8, rem = i & 255, l2 = rem >> 2, j = i & 3;
        whh2I[i] = gwhh[(128 + l2) * 64 + d4 * 4 + j];
    }
    for (int i = tid; i < 4096; i += TPB) {
        int d2 = i >> 8, rem = i & 255, l2 = rem >> 2, sub = rem & 3;
        int dd = d2 * 2 + (sub >> 1), which = sub & 1;
        lwhI[i] = lwhh[(which ? 64 + l2 : l2) * 32 + dd];
    }
    if (b < NWB) {
        int r0 = b * 4 + wv;
        for (int k = 0; k < 4; ++k) toks[wv][k * 64 + l] = seq[r0 * 256 + k * 64 + l];
    }
    __syncthreads();

    // ================= VERIFIER BLOCK =================
    if (b == NWB) {
        int start = 3 + wv * 64;
        int endt = (wv == 3) ? 255 : (start + 63);
        int myf = 1 << 30;
        for (int ti = start; ti <= endt; ++ti) {
            unsigned long long sum = 0; int spin = 0; bool bad = false;
            for (;;) {
                bool all16 = true; sum = 0;
                #pragma unroll
                for (int k = 0; k < 16; ++k) {
                    unsigned long long v = __hip_atomic_load(
                        &slots[(size_t)ti * 1024 + k * 64 + l],
                        __ATOMIC_RELAXED, __HIP_MEMORY_SCOPE_AGENT);
                    all16 &= ((v >> 44) == 1ULL);
                    sum += v & MASK44;
                }
                if (__all(all16)) break;
                if (++spin > SPIN_BOUND) { bad = true; break; }
                __builtin_amdgcn_s_sleep(1);
            }
            if (bad) { myf = -1; break; }
            #pragma unroll
            for (int o = 32; o; o >>= 1) sum += __shfl_xor(sum, o);
            if ((sum & MASK44) > THRESH) { myf = ti; break; }
        }
        if (l == 0) firstf[wv] = myf;
        __syncthreads();
        if (wv != 0) return;
        int tc = min(min(firstf[0], firstf[1]), min(firstf[2], firstf[3]));
        if (tc < 0) {  // broken co-residency: release workers, sentinel rate
            if (l == 0) { __hip_atomic_store(verdict, 1ULL, __ATOMIC_RELAXED, __HIP_MEMORY_SCOPE_AGENT); out[65536] = -1234.f; }
            return;
        }
        if (tc > 255) {  // all clear
            if (l == 0) { __hip_atomic_store(verdict, 1ULL, __ATOMIC_RELAXED, __HIP_MEMORY_SCOPE_AGENT); out[65536] = 0.f; }
            return;
        }
        if (l == 0) __hip_atomic_store(verdict, 3ULL | ((unsigned long long)tc << 8),
                                       __ATOMIC_RELAXED, __HIP_MEMORY_SCOPE_AGENT);
        // sequential careful verification (rare path)
        int cnt = 1; bool okr = true;
        for (int ti = tc + 1; ti <= 255; ++ti) {
            unsigned long long sum = 0; int spin = 0;
            for (;;) {
                bool all16 = true; sum = 0;
                #pragma unroll
                for (int k = 0; k < 16; ++k) {
                    unsigned long long v = __hip_atomic_load(
                        &slots[(size_t)ti * 1024 + k * 64 + l],
                        __ATOMIC_RELAXED, __HIP_MEMORY_SCOPE_AGENT);
                    all16 &= ((v >> 44) == 2ULL);
                    sum += v & MASK44;
                }
                if (__all(all16)) break;
                if (++spin > SPIN_BOUND) { okr = false; break; }
                __builtin_amdgcn_s_sleep(1);
            }
            if (!okr) break;
            #pragma unroll
            for (int o = 32; o; o >>= 1) sum += __shfl_xor(sum, o);
            int dec = ((sum & MASK44) > THRESH) ? 1 : 0;
            if (l == 0) __hip_atomic_store(&flags[ti], 1ULL | ((unsigned long long)dec << 1),
                                           __ATOMIC_RELAXED, __HIP_MEMORY_SCOPE_AGENT);
            cnt += dec;
        }
        if (l == 0) out[65536] = okr ? (float)cnt / 256.f : -1234.f;
        return;
    }

    // ================= WORKER =================
    int r = b * 4 + wv;

    // whh0/whh1 -> registers via wave-local PX scratch (PX not yet live)
    float whh0[64], whh1[64];
    float* pscr = &PX[wv][0][0];
    for (int c = 0; c < 8; ++c) {
        for (int r2 = 0; r2 < 8; ++r2) pscr[r2 * 64 + l] = gwhh[(c * 8 + r2) * 64 + l];
        if ((l >> 3) == c) {
            #pragma unroll
            for (int d = 0; d < 64; ++d) whh0[d] = pscr[(l & 7) * 64 + d];
        }
    }
    for (int c = 0; c < 8; ++c) {
        for (int r2 = 0; r2 < 8; ++r2) pscr[r2 * 64 + l] = gwhh[(64 + c * 8 + r2) * 64 + l];
        if ((l >> 3) == c) {
            #pragma unroll
            for (int d = 0; d < 64; ++d) whh1[d] = pscr[(l & 7) * 64 + d];
        }
    }

    float g0b = gbhh[l], g1b = gbhh[64 + l], g2b = gbhh[128 + l];
    float lb0 = lbih[l] + lbhh[l], lb1 = lbih[64 + l] + lbhh[64 + l];
    float avr = avec[l];
    float cv0 = cvec[l], cv1 = cvec[64 + l], cv2 = cvec[128 + l];
    float twr = (l < 32) ? tw[l] : 0.f;
    float tb0 = tb[0];
    const float* mrow = memory + (size_t)r * 16384;
    bool brk = false;

    // rare-path attention: reg/shfl only, no LDS scratch
    auto attention = [&](int prv, float& a0, float& a1, float& a2) {
        float qk = avr;
        #pragma unroll
        for (int d4 = 0; d4 < 16; ++d4) {
            float4 hv = *(const float4*)&ring[wv][prv][d4 * 4];
            qk += hv.x * A_ws[(d4 * 4) * 64 + l] + hv.y * A_ws[(d4 * 4 + 1) * 64 + l]
                + hv.z * A_ws[(d4 * 4 + 2) * 64 + l] + hv.w * A_ws[(d4 * 4 + 3) * 64 + l];
        }
        float sc[4];
        for (int k = 0; k < 4; ++k) {
            const float* mp = mrow + (size_t)(k * 64 + l) * 64;
            float s = 0.f;
            for (int d4 = 0; d4 < 16; ++d4) {
                float4 m4 = *(const float4*)(mp + d4 * 4);
                s += __shfl(qk, d4 * 4) * m4.x + __shfl(qk, d4 * 4 + 1) * m4.y
                   + __shfl(qk, d4 * 4 + 2) * m4.z + __shfl(qk, d4 * 4 + 3) * m4.w;
            }
            sc[k] = s;
        }
        float mx = fmaxf(fmaxf(sc[0], sc[1]), fmaxf(sc[2], sc[3]));
        for (int o = 32; o; o >>= 1) mx = fmaxf(mx, __shfl_xor(mx, o));
        float den = 0.f;
        for (int k = 0; k < 4; ++k) { sc[k] = expf(sc[k] - mx); den += sc[k]; }
        for (int o = 32; o; o >>= 1) den += __shfl_xor(den, o);
        float u = 0.f;
        for (int m = 0; m < 256; ++m) {
            float wm = __shfl(sc[m >> 6], m & 63);
            u += wm * mrow[(size_t)m * 64 + l];
        }
        u /= den;
        a0 += cv0; a1 += cv1; a2 += cv2;
        for (int e = 0; e < 64; ++e) {
            float ue = __shfl(u, e);
            a0 += ue * Gw[e * 192 + l];
            a1 += ue * Gw[e * 192 + 64 + l];
            a2 += ue * Gw[e * 192 + 128 + l];
        }
    };

    // mode 0: fast/speculative (publish tag1) | 1: replay (silent) | 2: careful (tag2 + flag waits)
    auto run = [&](int tbeg, int tend, int mode, bool fire0) {
        bool fire = fire0;
        for (int t = tbeg; t <= tend; ++t) {
            int cur = t & 1, prv = cur ^ 1;
            const float* tp = tokproj + toks[wv][t] * 192;
            float gi0 = tp[l], gi1 = tp[64 + l], gi2 = tp[128 + l];
            float gh0 = g0b, gh1 = g1b, gh2 = g2b;
            #pragma unroll
            for (int d4 = 0; d4 < 16; ++d4) {
                float4 hv = *(const float4*)&ring[wv][prv][d4 * 4];
                float4 w2 = *(const float4*)&whh2I[d4 * 256 + l * 4];
                gh0 += hv.x * whh0[4 * d4] + hv.y * whh0[4 * d4 + 1] + hv.z * whh0[4 * d4 + 2] + hv.w * whh0[4 * d4 + 3];
                gh1 += hv.x * whh1[4 * d4] + hv.y * whh1[4 * d4 + 1] + hv.z * whh1[4 * d4 + 2] + hv.w * whh1[4 * d4 + 3];
                gh2 += hv.x * w2.x + hv.y * w2.y + hv.z * w2.z + hv.w * w2.w;
            }
            if (fire) { attention(prv, gi0, gi1, gi2); fire = false; }
            float hp = ring[wv][prv][l];
            float r_ = sigf(gi0 + gh0), z_ = sigf(gi1 + gh1);
            float n_ = tanhf(gi2 + r_ * gh2);
            float hn = (1.f - z_) * n_ + z_ * hp;
            ring[wv][cur][l] = hn;

            float p0 = lb0, p1 = lb1;
            #pragma unroll
            for (int d4 = 0; d4 < 16; ++d4) {
                float4 hv = *(const float4*)&ring[wv][cur][d4 * 4];
                float4 wa = *(const float4*)&wlI[d4 * 512 + l * 8];
                float4 wb = *(const float4*)&wlI[d4 * 512 + l * 8 + 4];
                p0 += hv.x * wa.x + hv.y * wa.z + hv.z * wb.x + hv.w * wb.z;
                p1 += hv.x * wa.y + hv.y * wa.w + hv.z * wb.y + hv.w * wb.w;
            }
            PX[wv][t & 3][l] = p0; PX[wv][t & 3][64 + l] = p1;

            if (t >= 3) {
                float hh = 0.f, cc = 0.f;
                #pragma unroll
                for (int k = 0; k < 4; ++k) {
                    float q0, q1;
                    if (k == 3) { q0 = p0; q1 = p1; }
                    else { int s2 = (t - 3 + k) & 3; q0 = PX[wv][s2][l]; q1 = PX[wv][s2][64 + l]; }
                    if (k) {
                        #pragma unroll
                        for (int d2 = 0; d2 < 16; ++d2) {
                            float4 lw = *(const float4*)&lwhI[d2 * 256 + l * 4];
                            float s0 = __shfl(hh, d2 * 2), s1 = __shfl(hh, d2 * 2 + 1);
                            q0 += s0 * lw.x + s1 * lw.z;
                            q1 += s0 * lw.y + s1 * lw.w;
                        }
                    }
                    float f_ = __shfl(q0, l + 32), o_ = __shfl(q1, l + 32);
                    float ig = sigf(q0), ff = sigf(f_), gg = tanhf(q1), oo = sigf(o_);
                    float ncc = ff * cc + ig * gg;
                    float nhh = oo * tanhf(ncc);
                    if (l < 32) { cc = ncc; hh = nhh; }
                }
                float pp = (l < 32) ? hh * twr : 0.f;
                #pragma unroll
                for (int o = 32; o; o >>= 1) pp += __shfl_xor(pp, o);
                if (mode != 1 && l == 0) {
                    float prob = sigf(pp + tb0);
                    unsigned long long q = (unsigned long long)llrint((double)prob * 1073741824.0);
                    unsigned long long tag = (mode == 0) ? 1ULL : 2ULL;
                    __hip_atomic_store(&slots[(size_t)t * 1024 + r], (tag << 44) | q,
                                       __ATOMIC_RELAXED, __HIP_MEMORY_SCOPE_AGENT);
                }
                if (mode == 2 && t < 255) {
                    unsigned long long fv = 0; int spin = 0;
                    for (;;) {
                        fv = __hip_atomic_load(&flags[t], __ATOMIC_RELAXED, __HIP_MEMORY_SCOPE_AGENT);
                        if (fv & 1ULL) break;
                        if (++spin > SPIN_BOUND) { brk = true; break; }
                        __builtin_amdgcn_s_sleep(1);
                    }
                    fire = !brk && ((fv >> 1) & 1ULL);
                }
            }
        }
    };

    // ---- fast speculative pass: zero cross-block communication ----
    ring[wv][1][l] = 0.f;               // h_{-1}
    run(0, 255, 0, false);

    // ---- wait for the verdict ----
    unsigned long long vd = 0; int spin = 0;
    for (;;) {
        vd = __hip_atomic_load(verdict, __ATOMIC_RELAXED, __HIP_MEMORY_SCOPE_AGENT);
        if (vd & 1ULL) break;
        if (++spin > SPIN_BOUND) { brk = true; break; }
        __builtin_amdgcn_s_sleep(2);
    }
    if (!brk && (vd & 2ULL)) {          // fire at tc: exact replay + careful tail
        int tc = (int)(vd >> 8);
        ring[wv][1][l] = 0.f;
        run(0, tc, 1, false);
        if (tc < 255) run(tc + 1, 255, 2, true);
    }

    // ---- logits ----
    float sL = hb[l];
    #pragma unroll
    for (int d4 = 0; d4 < 16; ++d4) {
        float4 hv = *(const float4*)&ring[wv][1][d4 * 4];
        sL += hv.x * headT[(d4 * 4) * 64 + l] + hv.y * headT[(d4 * 4 + 1) * 64 + l]
            + hv.z * headT[(d4 * 4 + 2) * 64 + l] + hv.w * headT[(d4 * 4 + 3) * 64 + l];
    }
    out[r * 64 + l] = sL;
}

extern "C" void kernel_launch(void* const* d_in, const int* in_sizes, int n_in,
                              void* d_out, int out_size, void* d_ws, size_t ws_size,
                              hipStream_t stream)
{
    const int*   seq    = (const int*)d_in[0];
    const float* memory = (const float*)d_in[1];
    const float* embed  = (const float*)d_in[2];
    const float* gwih   = (const float*)d_in[3];
    const float* gwhh   = (const float*)d_in[4];
    const float* gbih   = (const float*)d_in[5];
    const float* gbhh   = (const float*)d_in[6];
    const float* qw     = (const float*)d_in[7];
    const float* qb     = (const float*)d_in[8];
    const float* kw     = (const float*)d_in[9];
    // d_in[10] = k_b : cancels in softmax, unused
    const float* vw     = (const float*)d_in[11];
    const float* vb     = (const float*)d_in[12];
    const float* lwih   = (const float*)d_in[13];
    const float* lwhh   = (const float*)d_in[14];
    const float* lbih   = (const float*)d_in[15];
    const float* lbhh   = (const float*)d_in[16];
    const float* tw     = (const float*)d_in[17];
    const float* tb     = (const float*)d_in[18];
    const float* hw     = (const float*)d_in[19];
    const float* hb     = (const float*)d_in[20];
    float* ws = (float*)d_ws;
    float* out = (float*)d_out;

    prep_k<<<386, 64, 0, stream>>>(embed, gwih, gbih, qw, qb, kw, vw, vb, hw, ws);
    persist_k<<<NWB + 1, TPB, 0, stream>>>(seq, memory, gwhh, gbhh, lwih, lwhh,
                                           lbih, lbhh, tw, tb, hb, ws, out);
}

// Round 9
// 987.738 us; speedup vs baseline: 12.9944x; 1.9064x over previous
//
#include <hip/hip_runtime.h>
#include <math.h>

#define TPB  256
#define NBLK 256
#define SPIN_BOUND (1 << 18)

// ws float offsets
#define OFF_TOKPROJ 0         // 64*192 = 12288
#define OFF_A       12288     // 64*64
#define OFF_AVEC    16384     // 64
#define OFF_G       16448     // 64*192
#define OFF_CVEC    28736     // 192
#define OFF_FLAGS   28928     // 256 u64 = 512 f
#define OFF_SLOTS   29440     // 256*1024 u64 = 524288 f
#define ZERO_LEN    (512 + 524288)

#define MASK44 ((1ULL << 44) - 1)
#define THRESH (512ULL << 30)  // mean > 0.5  <=>  sum(prob*2^30) > 512*2^30

__device__ __forceinline__ float sigf(float x) { return 1.f / (1.f + expf(-x)); }
__device__ __forceinline__ float rlf(float v, int lane) {
    return __uint_as_float(__builtin_amdgcn_readlane(__float_as_uint(v), lane));
}

// ---------------- prep: fused tables, zero flags+slots ----------------
__global__ __launch_bounds__(64) void prep_k(
    const float* __restrict__ embed, const float* __restrict__ gwih,
    const float* __restrict__ gbih, const float* __restrict__ qw,
    const float* __restrict__ qb, const float* __restrict__ kw,
    const float* __restrict__ vw, const float* __restrict__ vb,
    float* __restrict__ ws)
{
    int blk = blockIdx.x, l = threadIdx.x;
    float* tokproj = ws + OFF_TOKPROJ;
    float* A = ws + OFF_A;
    float* avec = ws + OFF_AVEC;
    float* G = ws + OFF_G;
    float* cvec = ws + OFF_CVEC;

    if (blk < 64) {
        int v = blk;
        for (int j = l; j < 192; j += 64) {
            float s = gbih[j];
            for (int d = 0; d < 64; ++d) s += embed[v * 64 + d] * gwih[j * 128 + d];
            tokproj[v * 192 + j] = s;
        }
    } else if (blk < 128) {
        int d = blk - 64;
        float s = 0.f;
        for (int e = 0; e < 64; ++e) s += qw[e * 64 + d] * kw[e * 64 + l];
        A[d * 64 + l] = s * 0.125f;   // 1/sqrt(64)
    } else if (blk < 192) {
        int e = blk - 128;
        for (int jj = 0; jj < 3; ++jj) {
            int j = jj * 64 + l;
            float s = 0.f;
            for (int d = 0; d < 64; ++d) s += vw[d * 64 + e] * gwih[j * 128 + 64 + d];
            G[e * 192 + j] = s;
        }
    } else if (blk == 192) {
        float s = 0.f;
        for (int e = 0; e < 64; ++e) s += qb[e] * kw[e * 64 + l];
        avec[l] = s * 0.125f;
        for (int jj = 0; jj < 3; ++jj) {
            int j = jj * 64 + l;
            float c = 0.f;
            for (int d = 0; d < 64; ++d) c += vb[d] * gwih[j * 128 + 64 + d];
            cvec[j] = c;
        }
    } else {
        // zero flags + slots: 128 blocks x 4100 floats = 524800
        int base = OFF_FLAGS + (blk - 193) * 4100;
        int end = OFF_FLAGS + ZERO_LEN;
        for (int i = base + l; i < base + 4100; i += 64)
            if (i < end) ws[i] = 0.f;
    }
}

// ---------------- persistent kernel: all-register, speculative ----------
__global__ __launch_bounds__(TPB, 1) void persist_k(
    const int* __restrict__ seq, const float* __restrict__ memory,
    const float* __restrict__ gwhh, const float* __restrict__ gbhh,
    const float* __restrict__ lwih, const float* __restrict__ lwhh,
    const float* __restrict__ lbih, const float* __restrict__ lbhh,
    const float* __restrict__ tw, const float* __restrict__ tb,
    const float* __restrict__ hb, const float* __restrict__ hw,
    float* __restrict__ ws, float* __restrict__ out)
{
    int tid = threadIdx.x, w = tid >> 6, l = tid & 63, b = blockIdx.x;
    int r = b * 4 + w;

    const float* tokproj = ws + OFF_TOKPROJ;
    const float* A_ws = ws + OFF_A;
    const float* avec = ws + OFF_AVEC;
    const float* Gw = ws + OFF_G;
    const float* cvec = ws + OFF_CVEC;
    unsigned long long* flags = (unsigned long long*)(ws + OFF_FLAGS);
    unsigned long long* slots = (unsigned long long*)(ws + OFF_SLOTS);

    __shared__ float PX[4][4][128];   // per-wave, lane-local only
    __shared__ int toks[4][256];      // per-wave
    __shared__ int tcLds;

    // ---- stage tokens (wave-local) ----
    for (int k = 0; k < 4; ++k) toks[w][k * 64 + l] = seq[r * 256 + k * 64 + l];

    // ---- all weights into registers (one-time, L2-served) ----
    float whh0[64], whh1[64], whh2[64], wl0[64], wl1[64], lwh0[32], lwh1[32];
    #pragma unroll
    for (int d4 = 0; d4 < 16; ++d4) {
        float4 a0 = *(const float4*)(gwhh + (size_t)l * 64 + d4 * 4);
        float4 a1 = *(const float4*)(gwhh + (size_t)(64 + l) * 64 + d4 * 4);
        float4 a2 = *(const float4*)(gwhh + (size_t)(128 + l) * 64 + d4 * 4);
        float4 b0 = *(const float4*)(lwih + (size_t)l * 64 + d4 * 4);
        float4 b1 = *(const float4*)(lwih + (size_t)(64 + l) * 64 + d4 * 4);
        whh0[d4*4] = a0.x; whh0[d4*4+1] = a0.y; whh0[d4*4+2] = a0.z; whh0[d4*4+3] = a0.w;
        whh1[d4*4] = a1.x; whh1[d4*4+1] = a1.y; whh1[d4*4+2] = a1.z; whh1[d4*4+3] = a1.w;
        whh2[d4*4] = a2.x; whh2[d4*4+1] = a2.y; whh2[d4*4+2] = a2.z; whh2[d4*4+3] = a2.w;
        wl0[d4*4] = b0.x; wl0[d4*4+1] = b0.y; wl0[d4*4+2] = b0.z; wl0[d4*4+3] = b0.w;
        wl1[d4*4] = b1.x; wl1[d4*4+1] = b1.y; wl1[d4*4+2] = b1.z; wl1[d4*4+3] = b1.w;
    }
    #pragma unroll
    for (int d4 = 0; d4 < 8; ++d4) {
        float4 c0 = *(const float4*)(lwhh + (size_t)l * 32 + d4 * 4);
        float4 c1 = *(const float4*)(lwhh + (size_t)(64 + l) * 32 + d4 * 4);
        lwh0[d4*4] = c0.x; lwh0[d4*4+1] = c0.y; lwh0[d4*4+2] = c0.z; lwh0[d4*4+3] = c0.w;
        lwh1[d4*4] = c1.x; lwh1[d4*4+1] = c1.y; lwh1[d4*4+2] = c1.z; lwh1[d4*4+3] = c1.w;
    }

    float g0b = gbhh[l], g1b = gbhh[64 + l], g2b = gbhh[128 + l];
    float lb0 = lbih[l] + lbhh[l], lb1 = lbih[64 + l] + lbhh[64 + l];
    float avr = avec[l];
    float cv0 = cvec[l], cv1 = cvec[64 + l], cv2 = cvec[128 + l];
    float twr = (l < 32) ? tw[l] : 0.f;
    float tb0 = tb[0];
    const float* mrow = memory + (size_t)r * 16384;
    float h = 0.f;
    bool brk = false;

    // rare-path attention on current h (= h_{t-1}); adds retrieved-fold into gi
    auto attention = [&](float& a0, float& a1, float& a2) {
        float qk = avr;
        #pragma unroll
        for (int d = 0; d < 64; ++d) qk += rlf(h, d) * A_ws[d * 64 + l];
        float sc[4];
        for (int k = 0; k < 4; ++k) {
            const float* mp = mrow + (size_t)(k * 64 + l) * 64;
            float s = 0.f;
            for (int d4 = 0; d4 < 16; ++d4) {
                float4 m4 = *(const float4*)(mp + d4 * 4);
                s += __shfl(qk, d4 * 4) * m4.x + __shfl(qk, d4 * 4 + 1) * m4.y
                   + __shfl(qk, d4 * 4 + 2) * m4.z + __shfl(qk, d4 * 4 + 3) * m4.w;
            }
            sc[k] = s;
        }
        float mx = fmaxf(fmaxf(sc[0], sc[1]), fmaxf(sc[2], sc[3]));
        for (int o = 32; o; o >>= 1) mx = fmaxf(mx, __shfl_xor(mx, o));
        float den = 0.f;
        #pragma unroll
        for (int k = 0; k < 4; ++k) { sc[k] = expf(sc[k] - mx); den += sc[k]; }
        for (int o = 32; o; o >>= 1) den += __shfl_xor(den, o);
        float u = 0.f;
        for (int m = 0; m < 256; ++m) {
            float wm = __shfl(sc[m >> 6], m & 63);
            u += wm * mrow[(size_t)m * 64 + l];
        }
        u /= den;
        a0 += cv0; a1 += cv1; a2 += cv2;
        for (int e = 0; e < 64; ++e) {
            float ue = __shfl(u, e);
            a0 += ue * Gw[e * 192 + l];
            a1 += ue * Gw[e * 192 + 64 + l];
            a2 += ue * Gw[e * 192 + 128 + l];
        }
    };

    // mode 0: speculative publish tag1 | 1: silent replay (no LSTM) | 2: careful tag2 + self-verify
    auto run = [&](int tbeg, int tend, int mode, bool fire0) -> int {
        bool fire = fire0;
        int decs = 0;
        for (int t = tbeg; t <= tend; ++t) {
            const float* tp = tokproj + toks[w][t] * 192;
            float gi0 = tp[l], gi1 = tp[64 + l], gi2 = tp[128 + l];
            float gh0 = g0b, gh1 = g1b, gh2 = g2b;
            #pragma unroll
            for (int d = 0; d < 64; ++d) {
                float s = rlf(h, d);
                gh0 += s * whh0[d]; gh1 += s * whh1[d]; gh2 += s * whh2[d];
            }
            if (fire) { attention(gi0, gi1, gi2); fire = false; }
            float r_ = sigf(gi0 + gh0), z_ = sigf(gi1 + gh1);
            float n_ = tanhf(gi2 + r_ * gh2);
            h = (1.f - z_) * n_ + z_ * h;

            float p0 = lb0, p1 = lb1;
            #pragma unroll
            for (int d = 0; d < 64; ++d) {
                float s = rlf(h, d);
                p0 += s * wl0[d]; p1 += s * wl1[d];
            }
            PX[w][t & 3][l] = p0; PX[w][t & 3][64 + l] = p1;

            if (t >= 3 && mode != 1) {
                float hh = 0.f, cc = 0.f;
                #pragma unroll
                for (int k = 0; k < 4; ++k) {
                    float q0, q1;
                    if (k == 3) { q0 = p0; q1 = p1; }
                    else { int s2 = (t - 3 + k) & 3; q0 = PX[w][s2][l]; q1 = PX[w][s2][64 + l]; }
                    if (k) {
                        #pragma unroll
                        for (int d = 0; d < 32; ++d) {
                            float s = rlf(hh, d);
                            q0 += s * lwh0[d]; q1 += s * lwh1[d];
                        }
                    }
                    float f_ = __shfl(q0, l + 32), o_ = __shfl(q1, l + 32);
                    float ig = sigf(q0), ff = sigf(f_), gg = tanhf(q1), oo = sigf(o_);
                    float ncc = ff * cc + ig * gg;
                    float nhh = oo * tanhf(ncc);
                    if (l < 32) { cc = ncc; hh = nhh; }
                }
                float pp = (l < 32) ? hh * twr : 0.f;
                #pragma unroll
                for (int o = 32; o; o >>= 1) pp += __shfl_xor(pp, o);
                if (l == 0) {
                    float prob = sigf(pp + tb0);
                    unsigned long long q = (unsigned long long)llrint((double)prob * 1073741824.0);
                    unsigned long long tag = (mode == 0) ? 1ULL : 2ULL;
                    __hip_atomic_store(&slots[(size_t)t * 1024 + r], (tag << 44) | q,
                                       __ATOMIC_RELAXED, __HIP_MEMORY_SCOPE_AGENT);
                }
                if (mode == 2) {   // rare path: self-verify this step's flag
                    const unsigned long long* sl = slots + (size_t)t * 1024;
                    unsigned long long sum = 0; int spin = 0; bool ok = true;
                    for (;;) {
                        bool all16 = true; sum = 0;
                        #pragma unroll
                        for (int k = 0; k < 16; ++k) {
                            unsigned long long v = __hip_atomic_load(
                                sl + k * 64 + l, __ATOMIC_RELAXED, __HIP_MEMORY_SCOPE_AGENT);
                            all16 &= ((v >> 44) == 2ULL);
                            sum += v & MASK44;
                        }
                        if (__all(all16)) break;
                        if (++spin > SPIN_BOUND) { ok = false; brk = true; break; }
                        __builtin_amdgcn_s_sleep(1);
                    }
                    #pragma unroll
                    for (int o = 32; o; o >>= 1) sum += __shfl_xor(sum, o);
                    int dec = (ok && (sum & MASK44) > THRESH) ? 1 : 0;
                    fire = (dec != 0);
                    decs += dec;
                }
            }
        }
        return decs;
    };

    // ---- speculative pass: zero communication ----
    run(0, 255, 0, false);

    // ---- distributed verification: block b verifies step 3+b ----
    if (w == 0) {
        if (b < 253) {
            int myt = 3 + b;
            const unsigned long long* sl = slots + (size_t)myt * 1024;
            unsigned long long sum = 0; int spin = 0; bool ok = true;
            for (;;) {
                bool all16 = true; sum = 0;
                #pragma unroll
                for (int k = 0; k < 16; ++k) {
                    unsigned long long v = __hip_atomic_load(
                        sl + k * 64 + l, __ATOMIC_RELAXED, __HIP_MEMORY_SCOPE_AGENT);
                    all16 &= ((v >> 44) == 1ULL);
                    sum += v & MASK44;
                }
                if (__all(all16)) break;
                if (++spin > SPIN_BOUND) { ok = false; brk = true; break; }
                __builtin_amdgcn_s_sleep(1);
            }
            #pragma unroll
            for (int o = 32; o; o >>= 1) sum += __shfl_xor(sum, o);
            int dec = (ok && (sum & MASK44) > THRESH) ? 1 : 0;
            if (l == 0)
                __hip_atomic_store(&flags[myt], 1ULL | ((unsigned long long)dec << 1),
                                   __ATOMIC_RELAXED, __HIP_MEMORY_SCOPE_AGENT);
        }
        // poll all flags, find first fire
        unsigned long long fl0 = 0, fl1 = 0, fl2 = 0, fl3 = 0;
        {
            int spin = 0;
            for (;;) {
                bool done = true;
                int t0 = 3 + l * 4;
                fl0 = __hip_atomic_load(&flags[t0], __ATOMIC_RELAXED, __HIP_MEMORY_SCOPE_AGENT);
                done &= (fl0 & 1ULL);
                if (t0 + 1 < 256) { fl1 = __hip_atomic_load(&flags[t0+1], __ATOMIC_RELAXED, __HIP_MEMORY_SCOPE_AGENT); done &= (fl1 & 1ULL); }
                if (t0 + 2 < 256) { fl2 = __hip_atomic_load(&flags[t0+2], __ATOMIC_RELAXED, __HIP_MEMORY_SCOPE_AGENT); done &= (fl2 & 1ULL); }
                if (t0 + 3 < 256) { fl3 = __hip_atomic_load(&flags[t0+3], __ATOMIC_RELAXED, __HIP_MEMORY_SCOPE_AGENT); done &= (fl3 & 1ULL); }
                if (__all(done)) break;
                if (++spin > SPIN_BOUND) { brk = true; break; }
                __builtin_amdgcn_s_sleep(1);
            }
        }
        int mymin = 1 << 30;
        int t0 = 3 + l * 4;
        if (!brk) {
            if ((fl0 >> 1) & 1ULL) mymin = min(mymin, t0);
            if (t0 + 1 < 256 && ((fl1 >> 1) & 1ULL)) mymin = min(mymin, t0 + 1);
            if (t0 + 2 < 256 && ((fl2 >> 1) & 1ULL)) mymin = min(mymin, t0 + 2);
            if (t0 + 3 < 256 && ((fl3 >> 1) & 1ULL)) mymin = min(mymin, t0 + 3);
        }
        #pragma unroll
        for (int o = 32; o; o >>= 1) mymin = min(mymin, __shfl_xor(mymin, o));
        if (l == 0) tcLds = mymin;
    }
    __syncthreads();
    int tc = tcLds;

    // ---- fire path (rare): exact replay + careful tail ----
    int cnt = 0;
    if (tc <= 255) {
        h = 0.f;
        run(0, tc, 1, false);
        cnt = 1;
        if (tc < 255) cnt += run(tc + 1, 255, 2, true);
    }

    // ---- logits ----
    float sL = hb[l];
    #pragma unroll
    for (int d4 = 0; d4 < 16; ++d4) {
        float4 w4 = *(const float4*)(hw + (size_t)l * 64 + d4 * 4);
        sL += rlf(h, d4 * 4) * w4.x + rlf(h, d4 * 4 + 1) * w4.y
            + rlf(h, d4 * 4 + 2) * w4.z + rlf(h, d4 * 4 + 3) * w4.w;
    }
    out[r * 64 + l] = sL;

    if (b == 0 && w == 0 && l == 0)
        out[65536] = brk ? -1234.f : ((tc > 255) ? 0.f : (float)cnt / 256.f);
}

extern "C" void kernel_launch(void* const* d_in, const int* in_sizes, int n_in,
                              void* d_out, int out_size, void* d_ws, size_t ws_size,
                              hipStream_t stream)
{
    const int*   seq    = (const int*)d_in[0];
    const float* memory = (const float*)d_in[1];
    const float* embed  = (const float*)d_in[2];
    const float* gwih   = (const float*)d_in[3];
    const float* gwhh   = (const float*)d_in[4];
    const float* gbih   = (const float*)d_in[5];
    const float* gbhh   = (const float*)d_in[6];
    const float* qw     = (const float*)d_in[7];
    const float* qb     = (const float*)d_in[8];
    const float* kw     = (const float*)d_in[9];
    // d_in[10] = k_b : cancels in softmax, unused
    const float* vw     = (const float*)d_in[11];
    const float* vb     = (const float*)d_in[12];
    const float* lwih   = (const float*)d_in[13];
    const float* lwhh   = (const float*)d_in[14];
    const float* lbih   = (const float*)d_in[15];
    const float* lbhh   = (const float*)d_in[16];
    const float* tw     = (const float*)d_in[17];
    const float* tb     = (const float*)d_in[18];
    const float* hw     = (const float*)d_in[19];
    const float* hb     = (const float*)d_in[20];
    float* ws = (float*)d_ws;
    float* out = (float*)d_out;

    prep_k<<<321, 64, 0, stream>>>(embed, gwih, gbih, qw, qb, kw, vw, vb, ws);
    persist_k<<<NBLK, TPB, 0, stream>>>(seq, memory, gwhh, gbhh, lwih, lwhh,
                                        lbih, lbhh, tw, tb, hb, hw, ws, out);
}